// Round 1
// baseline (164.170 us; speedup 1.0000x reference)
//
#include <hip/hip_runtime.h>
#include <hip/hip_cooperative_groups.h>
#include <math.h>

namespace cg = cooperative_groups;

#define D 256
#define S 512
#define M 2048  // 4 * 512
#define CH (64 * 1024)  // 256KB workspace chunk in floats

typedef __attribute__((ext_vector_type(8))) short bf16x8;
typedef __attribute__((ext_vector_type(4))) float f32x4;

__device__ inline ushort f2bf(float f) {
    union { float f; unsigned u; } v; v.f = f;
    unsigned r = v.u + 0x7FFFu + ((v.u >> 16) & 1u);   // RNE
    return (ushort)(r >> 16);
}

// ---------------------------------------------------------------------------
// Phase 0: pack weights to bf16, transposed [n][k].  64 units.
// ---------------------------------------------------------------------------
__device__ void pack_unit(int blk,
    const float* __restrict__ W1, const float* __restrict__ Wv,
    const float* __restrict__ Wo, ushort* __restrict__ WAt,
    ushort* __restrict__ WBt, ushort* __restrict__ Wvt, ushort* __restrict__ Wot,
    ushort (*lt)[72])
{
    const int t = threadIdx.x;
    const int mat = blk >> 4;
    const int a0 = ((blk >> 2) & 3) * 64;   // dst row block (n = src col)
    const int b0 = (blk & 3) * 64;          // dst col block (k = src row)
    const int r = t >> 4;
    const int c = (t & 15) * 4;
#pragma unroll
    for (int p = 0; p < 4; ++p) {
        const int sr = b0 + p * 16 + r;
        float4 v;
        if (mat == 0) {
            float4 wa = *(const float4*)(W1 + (size_t)sr * 256 + a0 + c);
            float4 wc = *(const float4*)(W1 + (size_t)(512 + sr) * 256 + a0 + c);
            v = make_float4(wa.x + wc.x, wa.y + wc.y, wa.z + wc.z, wa.w + wc.w);
        } else if (mat == 1) {
            float4 wb = *(const float4*)(W1 + (size_t)(256 + sr) * 256 + a0 + c);
            float4 wc = *(const float4*)(W1 + (size_t)(512 + sr) * 256 + a0 + c);
            v = make_float4(wb.x - wc.x, wb.y - wc.y, wb.z - wc.z, wb.w - wc.w);
        } else if (mat == 2) {
            v = *(const float4*)(Wv + (size_t)sr * 256 + a0 + c);
        } else {
            v = *(const float4*)(Wo + (size_t)sr * 256 + a0 + c);
        }
        lt[p * 16 + r][c + 0] = f2bf(v.x);
        lt[p * 16 + r][c + 1] = f2bf(v.y);
        lt[p * 16 + r][c + 2] = f2bf(v.z);
        lt[p * 16 + r][c + 3] = f2bf(v.w);
    }
    __syncthreads();
    ushort* dst = (mat == 0) ? WAt : (mat == 1) ? WBt : (mat == 2) ? Wvt : Wot;
#pragma unroll
    for (int p = 0; p < 4; ++p) {
        const int dr = p * 16 + r;
        ushort4 o = make_ushort4(lt[c + 0][dr], lt[c + 1][dr],
                                 lt[c + 2][dr], lt[c + 3][dr]);
        *(ushort4*)(dst + (size_t)(a0 + dr) * 256 + b0 + c) = o;
    }
    __syncthreads();   // protect lt reuse by a later unit/phase
}

// ---------------------------------------------------------------------------
// Phase 1: MFMA QKV.  384 units (12 n-blocks x 32 m-blocks).
// ---------------------------------------------------------------------------
__device__ void qkv_unit(int bn, int bm,
    const float* __restrict__ x, const ushort* __restrict__ WAt,
    const ushort* __restrict__ WBt, const ushort* __restrict__ Wvt,
    const float* __restrict__ b1, const float* __restrict__ bv,
    float* __restrict__ hi, float* __restrict__ hj, ushort* __restrict__ vals_t,
    ushort (*T)[72])
{
    const int n0 = bn * 64, m0 = bm * 64;
    const int region = n0 >> 8, c0 = n0 & 255;
    const ushort* Bt = (region == 0) ? WAt : (region == 1) ? WBt : Wvt;
    const int t = threadIdx.x, w = t >> 6, l = t & 63;
    const int q = l >> 4, ln = l & 15;
    const int wm = (w >> 1) * 32, wn = (w & 1) * 32;

    f32x4 acc[2][2] = {};
    for (int k0 = 0; k0 < 256; k0 += 32) {
        union { bf16x8 v; ushort s[8]; } a[2];
        bf16x8 b[2];
#pragma unroll
        for (int mt = 0; mt < 2; ++mt) {
            const float* xr = x + (size_t)(m0 + wm + mt * 16 + ln) * 256 + k0 + q * 8;
            float4 u0 = *(const float4*)xr;
            float4 u1 = *(const float4*)(xr + 4);
            a[mt].s[0] = f2bf(u0.x); a[mt].s[1] = f2bf(u0.y);
            a[mt].s[2] = f2bf(u0.z); a[mt].s[3] = f2bf(u0.w);
            a[mt].s[4] = f2bf(u1.x); a[mt].s[5] = f2bf(u1.y);
            a[mt].s[6] = f2bf(u1.z); a[mt].s[7] = f2bf(u1.w);
        }
#pragma unroll
        for (int nt = 0; nt < 2; ++nt)
            b[nt] = *(const bf16x8*)(Bt + (size_t)(c0 + wn + nt * 16 + ln) * 256 + k0 + q * 8);
#pragma unroll
        for (int mt = 0; mt < 2; ++mt)
#pragma unroll
            for (int nt = 0; nt < 2; ++nt)
                acc[mt][nt] = __builtin_amdgcn_mfma_f32_16x16x32_bf16(a[mt].v, b[nt], acc[mt][nt], 0, 0, 0);
    }

    if (region < 2) {
        float* dst = (region == 0) ? hi : hj;
#pragma unroll
        for (int nt = 0; nt < 2; ++nt) {
            const int col = c0 + wn + nt * 16 + ln;
            const float bias = (region == 0) ? b1[col] : 0.f;
#pragma unroll
            for (int mt = 0; mt < 2; ++mt)
#pragma unroll
                for (int r = 0; r < 4; ++r) {
                    const int row = m0 + wm + mt * 16 + q * 4 + r;
                    dst[(size_t)row * 256 + col] = acc[mt][nt][r] + bias;
                }
        }
    } else {
        // stage bias-added bf16 into T[col_local][row_local], then store transposed
#pragma unroll
        for (int nt = 0; nt < 2; ++nt) {
            const int cl = wn + nt * 16 + ln;
            const float bias = bv[c0 + cl];
#pragma unroll
            for (int mt = 0; mt < 2; ++mt)
#pragma unroll
                for (int r = 0; r < 4; ++r)
                    T[cl][wm + mt * 16 + q * 4 + r] = f2bf(acc[mt][nt][r] + bias);
        }
        __syncthreads();
        const int bb = m0 >> 9, jloc = m0 & 511;
#pragma unroll
        for (int p = 0; p < 2; ++p) {
            const int idx = p * 256 + t;
            const int e_l = idx & 63, jc = (idx >> 6) * 8;
            *(uint4*)(vals_t + ((size_t)(bb * 256 + c0 + e_l)) * 512 + jloc + jc) =
                *(const uint4*)&T[e_l][jc];
        }
        __syncthreads();   // protect T reuse
    }
}

// ---------------------------------------------------------------------------
// Phase 2: scores, 64i x 32j tiles.  288 active units.
// ---------------------------------------------------------------------------
__device__ void scores_unit(int jt, int it, int bb,
    const float* __restrict__ hi, const float* __restrict__ hj,
    const float* __restrict__ w2, float* __restrict__ sc,
    float (*His)[64], float (*Sst)[36], float* w2s)
{
    const int i0 = it * 64, j0 = jt * 32;
    const int t = threadIdx.x, w = t >> 6, l = t & 63;
    const int q = l >> 4, ln = l & 15;

    if (t < 64) *(float4*)&w2s[t * 4] = *(const float4*)(w2 + t * 4);

    const int si = t & 63, sh_ = (t >> 6) * 8;
    const float* hisrc = hi + (size_t)((bb << 9) + i0 + si) * 256 + sh_;
    const int jrow = w * 8 + q * 2;
    const float* hj0 = hj + (size_t)((bb << 9) + j0 + jrow) * 256;
    const float* hj1 = hj0 + 256;

    float acc00 = 0.f, acc01 = 0.f, acc10 = 0.f, acc11 = 0.f;
    float acc20 = 0.f, acc21 = 0.f, acc30 = 0.f, acc31 = 0.f;

    for (int hc = 0; hc < 256; hc += 32) {
        float4 a0 = *(const float4*)(hisrc + hc);
        float4 a1 = *(const float4*)(hisrc + hc + 4);
        float e0[32], e1[32];
#pragma unroll
        for (int c = 0; c < 8; ++c) {
            *(float4*)&e0[c * 4] = *(const float4*)(hj0 + hc + c * 4);
            *(float4*)&e1[c * 4] = *(const float4*)(hj1 + hc + c * 4);
        }
        __syncthreads();   // protect previous chunk's (or unit's) His reads
        His[sh_ + 0][si] = a0.x; His[sh_ + 1][si] = a0.y;
        His[sh_ + 2][si] = a0.z; His[sh_ + 3][si] = a0.w;
        His[sh_ + 4][si] = a1.x; His[sh_ + 5][si] = a1.y;
        His[sh_ + 6][si] = a1.z; His[sh_ + 7][si] = a1.w;
        __syncthreads();
#pragma unroll
        for (int h = 0; h < 32; ++h) {
            float4 a = *(const float4*)&His[h][ln * 4];
            const float wv = w2s[hc + h];
            const float f0 = e0[h], f1 = e1[h];
            acc00 += fmaxf(a.x + f0, 0.f) * wv;
            acc01 += fmaxf(a.x + f1, 0.f) * wv;
            acc10 += fmaxf(a.y + f0, 0.f) * wv;
            acc11 += fmaxf(a.y + f1, 0.f) * wv;
            acc20 += fmaxf(a.z + f0, 0.f) * wv;
            acc21 += fmaxf(a.z + f1, 0.f) * wv;
            acc30 += fmaxf(a.w + f0, 0.f) * wv;
            acc31 += fmaxf(a.w + f1, 0.f) * wv;
        }
    }

    Sst[ln * 4 + 0][jrow] = acc00;  Sst[ln * 4 + 0][jrow + 1] = acc01;
    Sst[ln * 4 + 1][jrow] = acc10;  Sst[ln * 4 + 1][jrow + 1] = acc11;
    Sst[ln * 4 + 2][jrow] = acc20;  Sst[ln * 4 + 2][jrow + 1] = acc21;
    Sst[ln * 4 + 3][jrow] = acc30;  Sst[ln * 4 + 3][jrow + 1] = acc31;
    __syncthreads();
    const int i_l = t >> 2, jc = (t & 3) * 8;
    float* dst = sc + ((size_t)bb << 18) + (size_t)(i0 + i_l) * 512 + j0 + jc;
    *(float4*)dst       = *(const float4*)&Sst[i_l][jc];
    *(float4*)(dst + 4) = *(const float4*)&Sst[i_l][jc + 4];
}

// ---------------------------------------------------------------------------
// Phase 3: softmax.  256 units x 8 rows; each wave handles 2 rows in parallel.
// Reads the full 512-wide row (poison beyond j<i is select-masked out).
// ---------------------------------------------------------------------------
__device__ void softmax_rows(int bid, const float* __restrict__ sc,
                             ushort* __restrict__ attn_bf)
{
    const int t = threadIdx.x, w = t >> 6, l = t & 63;
    const int j0 = l * 8;
#pragma unroll
    for (int s = 0; s < 2; ++s) {
        const int row = bid * 8 + w * 2 + s;
        const int b = row >> 9, i = row & 511;
        const float* srow = sc + ((size_t)b << 18) + (size_t)i * S;
        float v[8];
        *(float4*)&v[0] = *(const float4*)(srow + j0);
        *(float4*)&v[4] = *(const float4*)(srow + j0 + 4);
        float mx = -3.0e38f;
#pragma unroll
        for (int k = 0; k < 8; ++k) {
            v[k] = (j0 + k < i) ? v[k] : -3.0e38f;   // mask BEFORE any use (poison-safe)
            mx = fmaxf(mx, v[k]);
        }
#pragma unroll
        for (int off = 32; off; off >>= 1) mx = fmaxf(mx, __shfl_xor(mx, off, 64));
        float e[8];
        float sum = 0.f;
#pragma unroll
        for (int k = 0; k < 8; ++k) {
            e[k] = __expf(v[k] - mx);                // invalid: exp(-3e38 - mx) -> 0
            sum += (j0 + k < i) ? e[k] : 0.f;
        }
#pragma unroll
        for (int off = 32; off; off >>= 1) sum += __shfl_xor(sum, off, 64);
        const float inv = (i > 0) ? (1.f / sum) : 0.f;   // i==0: all-zero row
        ushort o[8];
#pragma unroll
        for (int k = 0; k < 8; ++k)
            o[k] = (j0 + k < i) ? f2bf(e[k] * inv) : (ushort)0;
        ushort* arow = attn_bf + (size_t)row * S;
        *(ushort4*)(arow + j0)     = make_ushort4(o[0], o[1], o[2], o[3]);
        *(ushort4*)(arow + j0 + 4) = make_ushort4(o[4], o[5], o[6], o[7]);
    }
}

// ---------------------------------------------------------------------------
// Phase 4: MFMA PV.  128 units (4 n x 8 m x 4 b), causal K-truncation.
// ---------------------------------------------------------------------------
__device__ void pv_unit(int bn, int bm, int b,
    const ushort* __restrict__ attn_bf, const ushort* __restrict__ vals_t,
    ushort* __restrict__ msg_bf)
{
    const int n0 = bn * 64, m0 = bm * 64;
    const ushort* A = attn_bf + ((size_t)b << 18);
    const ushort* V = vals_t + (size_t)(b * 256) * 512;
    const int t = threadIdx.x, w = t >> 6, l = t & 63;
    const int q = l >> 4, ln = l & 15;
    const int wm = (w >> 1) * 32, wn = (w & 1) * 32;

    f32x4 acc[2][2] = {};
    const int kmax = m0 + 64;
    for (int k0 = 0; k0 < kmax; k0 += 32) {
        bf16x8 a[2], bb[2];
#pragma unroll
        for (int mt = 0; mt < 2; ++mt)
            a[mt] = *(const bf16x8*)(A + (size_t)(m0 + wm + mt * 16 + ln) * S + k0 + q * 8);
#pragma unroll
        for (int nt = 0; nt < 2; ++nt)
            bb[nt] = *(const bf16x8*)(V + (size_t)(n0 + wn + nt * 16 + ln) * 512 + k0 + q * 8);
#pragma unroll
        for (int mt = 0; mt < 2; ++mt)
#pragma unroll
            for (int nt = 0; nt < 2; ++nt)
                acc[mt][nt] = __builtin_amdgcn_mfma_f32_16x16x32_bf16(a[mt], bb[nt], acc[mt][nt], 0, 0, 0);
    }
#pragma unroll
    for (int nt = 0; nt < 2; ++nt) {
        const int col = n0 + wn + nt * 16 + ln;
#pragma unroll
        for (int mt = 0; mt < 2; ++mt)
#pragma unroll
            for (int r = 0; r < 4; ++r) {
                const int row = (b << 9) + m0 + wm + mt * 16 + q * 4 + r;
                msg_bf[(size_t)row * 256 + col] = f2bf(acc[mt][nt][r]);
            }
    }
}

// ---------------------------------------------------------------------------
// Phase 5: MFMA OUT + residual + bias + LayerNorm.  128 units x 16 rows.
// ---------------------------------------------------------------------------
__device__ void outln_unit(int r0,
    const ushort* __restrict__ msg_bf, const ushort* __restrict__ Wot,
    const float* __restrict__ x, const float* __restrict__ bo,
    const float* __restrict__ gamma, const float* __restrict__ beta,
    float* __restrict__ out, float (*redS)[4], float (*redQ)[4])
{
    const int t = threadIdx.x, w = t >> 6, l = t & 63;
    const int q = l >> 4, ln = l & 15;

    f32x4 acc[4] = {};
    for (int k0 = 0; k0 < 256; k0 += 32) {
        bf16x8 a = *(const bf16x8*)(msg_bf + (size_t)(r0 + ln) * 256 + k0 + q * 8);
#pragma unroll
        for (int nt = 0; nt < 4; ++nt) {
            bf16x8 bb = *(const bf16x8*)(Wot + (size_t)(w * 64 + nt * 16 + ln) * 256 + k0 + q * 8);
            acc[nt] = __builtin_amdgcn_mfma_f32_16x16x32_bf16(a, bb, acc[nt], 0, 0, 0);
        }
    }

    float sum[4] = {}, sq[4] = {};
#pragma unroll
    for (int nt = 0; nt < 4; ++nt) {
        const int col = w * 64 + nt * 16 + ln;
        const float bov = bo[col];
#pragma unroll
        for (int r = 0; r < 4; ++r) {
            const int row = r0 + q * 4 + r;
            float v = acc[nt][r] + x[(size_t)row * 256 + col] + bov;
            acc[nt][r] = v;
            sum[r] += v;
            sq[r] += v * v;
        }
    }
#pragma unroll
    for (int r = 0; r < 4; ++r) {
#pragma unroll
        for (int off = 1; off < 16; off <<= 1) {
            sum[r] += __shfl_xor(sum[r], off, 64);
            sq[r]  += __shfl_xor(sq[r],  off, 64);
        }
    }
    if (ln == 0) {
#pragma unroll
        for (int r = 0; r < 4; ++r) {
            redS[q * 4 + r][w] = sum[r];
            redQ[q * 4 + r][w] = sq[r];
        }
    }
    __syncthreads();
#pragma unroll
    for (int nt = 0; nt < 4; ++nt) {
        const int col = w * 64 + nt * 16 + ln;
        const float g = gamma[col], be = beta[col];
#pragma unroll
        for (int r = 0; r < 4; ++r) {
            const int rl = q * 4 + r;
            const float ts = redS[rl][0] + redS[rl][1] + redS[rl][2] + redS[rl][3];
            const float tq = redQ[rl][0] + redQ[rl][1] + redQ[rl][2] + redQ[rl][3];
            const float mu = ts * (1.f / 256.f);
            const float var = tq * (1.f / 256.f) - mu * mu;
            out[(size_t)(r0 + rl) * 256 + col] =
                (acc[nt][r] - mu) * rsqrtf(var + 1e-5f) * g + be;
        }
    }
}

// ---------------------------------------------------------------------------
// Shared-memory overlay for the fused kernel (max 18.4 KB).
// ---------------------------------------------------------------------------
union SharedU {
    ushort lt[64][72];                                        // pack / qkv-T
    struct { float His[32][64]; float Sst[64][36]; float w2s[256]; } s2;  // scores
    struct { float redS[16][4]; float redQ[16][4]; } s5;      // layernorm
};

// ---------------------------------------------------------------------------
// Fused cooperative kernel: 256 blocks x 256 threads (1 block/CU), 5 grid syncs.
// ---------------------------------------------------------------------------
__global__ __launch_bounds__(256) void fused_all(
    const float* __restrict__ x, const float* __restrict__ W1,
    const float* __restrict__ b1, const float* __restrict__ w2,
    const float* __restrict__ Wv, const float* __restrict__ bv,
    const float* __restrict__ Wo, const float* __restrict__ bo,
    const float* __restrict__ gamma, const float* __restrict__ beta,
    float* __restrict__ out, float* __restrict__ ws)
{
    float*  hi      = ws;
    float*  hj      = ws + 8 * (size_t)CH;
    float*  sc      = ws + 16 * (size_t)CH;
    ushort* WAt     = (ushort*)(ws + 32 * (size_t)CH);
    ushort* WBt     = (ushort*)(ws + 33 * (size_t)CH);
    ushort* Wvt     = (ushort*)(ws + 34 * (size_t)CH);
    ushort* Wot     = (ushort*)(ws + 35 * (size_t)CH);
    ushort* vals_t  = (ushort*)(ws + 36 * (size_t)CH);
    ushort* attn_bf = (ushort*)(ws + 40 * (size_t)CH);
    ushort* msg_bf  = (ushort*)(ws + 48 * (size_t)CH);

    __shared__ __align__(16) SharedU sh;
    cg::grid_group grid = cg::this_grid();
    const int bid = blockIdx.x;

    // P0: pack weights (64 units)
    if (bid < 64)
        pack_unit(bid, W1, Wv, Wo, WAt, WBt, Wvt, Wot, sh.lt);
    grid.sync();

    // P1: QKV gemm (384 units)
    for (int u = bid; u < 384; u += 256)
        qkv_unit(u % 12, u / 12, x, WAt, WBt, Wvt, b1, bv, hi, hj, vals_t, sh.lt);
    grid.sync();

    // P2: scores (288 causal tiles)
    for (int u = bid; u < 288; u += 256) {
        const int bb = u / 72, r = u % 72;
        int it = 0;
        while ((it + 1) * (it + 2) <= r) ++it;    // offset(it) = it*(it+1)
        const int jt = r - it * (it + 1);
        scores_unit(jt, it, bb, hi, hj, w2, sc, sh.s2.His, sh.s2.Sst, sh.s2.w2s);
    }
    grid.sync();

    // P3: softmax (8 rows per block, wave-parallel)
    softmax_rows(bid, sc, attn_bf);
    grid.sync();

    // P4: PV (128 units)
    if (bid < 128)
        pv_unit(bid & 3, (bid >> 2) & 7, bid >> 5, attn_bf, vals_t, msg_bf);
    grid.sync();

    // P5: out-proj + residual + LN (128 units)
    if (bid < 128)
        outln_unit(bid * 16, msg_bf, Wot, x, bo, gamma, beta, out,
                   sh.s5.redS, sh.s5.redQ);
}

// ---------------------------------------------------------------------------
// Fallback wrappers (verified 6-kernel pipeline) — used if cooperative launch
// is rejected (e.g. capture incompatibility).  Same device code.
// ---------------------------------------------------------------------------
__global__ __launch_bounds__(256) void pack_w_k(
    const float* __restrict__ W1, const float* __restrict__ Wv,
    const float* __restrict__ Wo, ushort* __restrict__ WAt,
    ushort* __restrict__ WBt, ushort* __restrict__ Wvt, ushort* __restrict__ Wot)
{
    __shared__ ushort lt[64][72];
    pack_unit(blockIdx.x, W1, Wv, Wo, WAt, WBt, Wvt, Wot, lt);
}

__global__ __launch_bounds__(256) void gemm_qkv_k(
    const float* __restrict__ x, const ushort* __restrict__ WAt,
    const ushort* __restrict__ WBt, const ushort* __restrict__ Wvt,
    const float* __restrict__ b1, const float* __restrict__ bv,
    float* __restrict__ hi, float* __restrict__ hj, ushort* __restrict__ vals_t)
{
    __shared__ ushort T[64][72];
    qkv_unit(blockIdx.x, blockIdx.y, x, WAt, WBt, Wvt, b1, bv, hi, hj, vals_t, T);
}

__global__ __launch_bounds__(256) void scores_k(
    const float* __restrict__ hi, const float* __restrict__ hj,
    const float* __restrict__ w2, float* __restrict__ sc)
{
    const int jt = blockIdx.x, it = blockIdx.y, bb = blockIdx.z;
    if (jt > 2 * it + 1) return;
    __shared__ __align__(16) float His[32][64];
    __shared__ __align__(16) float Sst[64][36];
    __shared__ float w2s[256];
    scores_unit(jt, it, bb, hi, hj, w2, sc, His, Sst, w2s);
}

__global__ __launch_bounds__(256) void softmax_k(
    const float* __restrict__ sc, ushort* __restrict__ attn_bf)
{
    softmax_rows(blockIdx.x, sc, attn_bf);
}

__global__ __launch_bounds__(256) void pv_k(
    const ushort* __restrict__ attn_bf, const ushort* __restrict__ vals_t,
    ushort* __restrict__ msg_bf)
{
    pv_unit(blockIdx.x, blockIdx.y, blockIdx.z, attn_bf, vals_t, msg_bf);
}

__global__ __launch_bounds__(256) void outln_k(
    const ushort* __restrict__ msg_bf, const ushort* __restrict__ Wot,
    const float* __restrict__ x, const float* __restrict__ bo,
    const float* __restrict__ gamma, const float* __restrict__ beta,
    float* __restrict__ out)
{
    __shared__ float redS[16][4];
    __shared__ float redQ[16][4];
    outln_unit(blockIdx.x * 16, msg_bf, Wot, x, bo, gamma, beta, out, redS, redQ);
}

// ---------------------------------------------------------------------------
extern "C" void kernel_launch(void* const* d_in, const int* in_sizes, int n_in,
                              void* d_out, int out_size, void* d_ws, size_t ws_size,
                              hipStream_t stream)
{
    (void)in_sizes; (void)n_in; (void)out_size; (void)ws_size;
    const float* x     = (const float*)d_in[0];
    const float* W1    = (const float*)d_in[1];
    const float* b1    = (const float*)d_in[2];
    const float* w2    = (const float*)d_in[3];
    const float* Wv    = (const float*)d_in[5];
    const float* bv    = (const float*)d_in[6];
    const float* Wo    = (const float*)d_in[7];
    const float* bo    = (const float*)d_in[8];
    const float* gamma = (const float*)d_in[9];
    const float* beta  = (const float*)d_in[10];
    float* out = (float*)d_out;
    float* ws  = (float*)d_ws;

    static int coop_ok = -1;   // -1 unknown, 1 works, 0 fall back
    if (coop_ok != 0) {
        void* kargs[] = { (void*)&x, (void*)&W1, (void*)&b1, (void*)&w2,
                          (void*)&Wv, (void*)&bv, (void*)&Wo, (void*)&bo,
                          (void*)&gamma, (void*)&beta, (void*)&out, (void*)&ws };
        hipError_t e = hipLaunchCooperativeKernel((const void*)fused_all,
                                                  dim3(256), dim3(256),
                                                  kargs, 0, stream);
        if (e == hipSuccess) { coop_ok = 1; return; }
        coop_ok = 0;
        (void)hipGetLastError();   // clear sticky error, fall through
    }

    // fallback: verified 6-kernel pipeline
    float*  hi      = ws;
    float*  hj      = ws + 8 * (size_t)CH;
    float*  sc      = ws + 16 * (size_t)CH;
    ushort* WAt     = (ushort*)(ws + 32 * (size_t)CH);
    ushort* WBt     = (ushort*)(ws + 33 * (size_t)CH);
    ushort* Wvt     = (ushort*)(ws + 34 * (size_t)CH);
    ushort* Wot     = (ushort*)(ws + 35 * (size_t)CH);
    ushort* vals_t  = (ushort*)(ws + 36 * (size_t)CH);
    ushort* attn_bf = (ushort*)(ws + 40 * (size_t)CH);
    ushort* msg_bf  = (ushort*)(ws + 48 * (size_t)CH);

    pack_w_k  <<<dim3(64),       256, 0, stream>>>(W1, Wv, Wo, WAt, WBt, Wvt, Wot);
    gemm_qkv_k<<<dim3(12, 32),   256, 0, stream>>>(x, WAt, WBt, Wvt, b1, bv, hi, hj, vals_t);
    scores_k  <<<dim3(16, 8, 4), 256, 0, stream>>>(hi, hj, w2, sc);
    softmax_k <<<dim3(256),      256, 0, stream>>>(sc, attn_bf);
    pv_k      <<<dim3(4, 8, 4),  256, 0, stream>>>(attn_bf, vals_t, msg_bf);
    outln_k   <<<dim3(128),      256, 0, stream>>>(msg_bf, Wot, x, bo, gamma, beta, out);
}

// Round 3
// 135.103 us; speedup vs baseline: 1.2151x; 1.2151x over previous
//
#include <hip/hip_runtime.h>
#include <math.h>

#define D 256
#define S 512
#define M 2048  // 4 * 512
#define CH (64 * 1024)  // 256KB workspace chunk in floats

typedef __attribute__((ext_vector_type(8))) short bf16x8;
typedef __attribute__((ext_vector_type(4))) float f32x4;

__device__ inline ushort f2bf(float f) {
    union { float f; unsigned u; } v; v.f = f;
    unsigned r = v.u + 0x7FFFu + ((v.u >> 16) & 1u);   // RNE
    return (ushort)(r >> 16);
}

// ---------------------------------------------------------------------------
// Kernel A: fused weight-pack + QKV MFMA GEMM.
//   Blocks 0..383: unit (bn = u%12 -> 64-col tile of region {WA|WB|Wv}, bm = u/12
//   -> 64-row tile of x).  Each block packs its own B-tile (bf16, [col][k]) into
//   LDS, then runs the K-loop.  Outputs: hi (+b1), hj, vals_t (bf16 transposed).
//   Blocks 384..399: pack Wot (Wo^T bf16) for kernel C.
// ---------------------------------------------------------------------------
__global__ __launch_bounds__(256) void qkv_pack_k(
    const float* __restrict__ x, const float* __restrict__ W1,
    const float* __restrict__ Wv, const float* __restrict__ Wo,
    const float* __restrict__ b1, const float* __restrict__ bv,
    float* __restrict__ hi, float* __restrict__ hj,
    ushort* __restrict__ vals_t, ushort* __restrict__ Wot)
{
    __shared__ union {
        ushort Bs[64][264];   // packed B-tile [col_local][k], +8 pad
        ushort lt[64][72];    // transpose staging (Wot pack / vals_t store)
    } sh;

    const int u = blockIdx.x;
    const int t = threadIdx.x;

    if (u >= 384) {
        // ---- Wot pack unit (16 blocks): Wot[n][k] = bf16(Wo[k][n]) ----
        const int unit = u - 384;
        const int a0 = (unit >> 2) * 64;   // dst row block (n = src col)
        const int b0 = (unit & 3) * 64;    // dst col block (k = src row)
        const int r = t >> 4;
        const int c = (t & 15) * 4;
#pragma unroll
        for (int p = 0; p < 4; ++p) {
            const int sr = b0 + p * 16 + r;
            float4 v = *(const float4*)(Wo + (size_t)sr * 256 + a0 + c);
            sh.lt[p * 16 + r][c + 0] = f2bf(v.x);
            sh.lt[p * 16 + r][c + 1] = f2bf(v.y);
            sh.lt[p * 16 + r][c + 2] = f2bf(v.z);
            sh.lt[p * 16 + r][c + 3] = f2bf(v.w);
        }
        __syncthreads();
#pragma unroll
        for (int p = 0; p < 4; ++p) {
            const int dr = p * 16 + r;
            ushort4 o = make_ushort4(sh.lt[c + 0][dr], sh.lt[c + 1][dr],
                                     sh.lt[c + 2][dr], sh.lt[c + 3][dr]);
            *(ushort4*)(Wot + (size_t)(a0 + dr) * 256 + b0 + c) = o;
        }
        return;
    }

    // ---- QKV gemm unit ----
    const int bn = u % 12, bm = u / 12;
    const int n0 = bn * 64, m0 = bm * 64;
    const int region = n0 >> 8, c0 = n0 & 255;

    // pack B-tile into LDS: Bs[cl][k] = bf16(Wsrc[k][c0+cl]), cl 0..63, k 0..255
    {
        const int cl4 = (t & 15) * 4;
        const int kb = (t >> 4) * 16;
#pragma unroll
        for (int kk = 0; kk < 16; ++kk) {
            const int k = kb + kk;
            float4 v;
            if (region == 0) {
                float4 wa = *(const float4*)(W1 + (size_t)k * 256 + c0 + cl4);
                float4 wc = *(const float4*)(W1 + (size_t)(512 + k) * 256 + c0 + cl4);
                v = make_float4(wa.x + wc.x, wa.y + wc.y, wa.z + wc.z, wa.w + wc.w);
            } else if (region == 1) {
                float4 wb = *(const float4*)(W1 + (size_t)(256 + k) * 256 + c0 + cl4);
                float4 wc = *(const float4*)(W1 + (size_t)(512 + k) * 256 + c0 + cl4);
                v = make_float4(wb.x - wc.x, wb.y - wc.y, wb.z - wc.z, wb.w - wc.w);
            } else {
                v = *(const float4*)(Wv + (size_t)k * 256 + c0 + cl4);
            }
            sh.Bs[cl4 + 0][k] = f2bf(v.x);
            sh.Bs[cl4 + 1][k] = f2bf(v.y);
            sh.Bs[cl4 + 2][k] = f2bf(v.z);
            sh.Bs[cl4 + 3][k] = f2bf(v.w);
        }
    }
    __syncthreads();

    const int w = t >> 6, l = t & 63;
    const int q = l >> 4, ln = l & 15;
    const int wm = (w >> 1) * 32, wn = (w & 1) * 32;

    f32x4 acc[2][2] = {};
    for (int k0 = 0; k0 < 256; k0 += 32) {
        union { bf16x8 v; ushort s[8]; } a[2];
        bf16x8 b[2];
#pragma unroll
        for (int mt = 0; mt < 2; ++mt) {
            const float* xr = x + (size_t)(m0 + wm + mt * 16 + ln) * 256 + k0 + q * 8;
            float4 u0 = *(const float4*)xr;
            float4 u1 = *(const float4*)(xr + 4);
            a[mt].s[0] = f2bf(u0.x); a[mt].s[1] = f2bf(u0.y);
            a[mt].s[2] = f2bf(u0.z); a[mt].s[3] = f2bf(u0.w);
            a[mt].s[4] = f2bf(u1.x); a[mt].s[5] = f2bf(u1.y);
            a[mt].s[6] = f2bf(u1.z); a[mt].s[7] = f2bf(u1.w);
        }
#pragma unroll
        for (int nt = 0; nt < 2; ++nt)
            b[nt] = *(const bf16x8*)&sh.Bs[wn + nt * 16 + ln][k0 + q * 8];
#pragma unroll
        for (int mt = 0; mt < 2; ++mt)
#pragma unroll
            for (int nt = 0; nt < 2; ++nt)
                acc[mt][nt] = __builtin_amdgcn_mfma_f32_16x16x32_bf16(a[mt].v, b[nt], acc[mt][nt], 0, 0, 0);
    }

    if (region < 2) {
        float* dst = (region == 0) ? hi : hj;
#pragma unroll
        for (int nt = 0; nt < 2; ++nt) {
            const int col = c0 + wn + nt * 16 + ln;
            const float bias = (region == 0) ? b1[col] : 0.f;
#pragma unroll
            for (int mt = 0; mt < 2; ++mt)
#pragma unroll
                for (int r = 0; r < 4; ++r) {
                    const int row = m0 + wm + mt * 16 + q * 4 + r;
                    dst[(size_t)row * 256 + col] = acc[mt][nt][r] + bias;
                }
        }
    } else {
        // stage bias-added bf16 into lt[col_local][row_local], store transposed
        __syncthreads();   // all Bs reads done before aliasing as lt
#pragma unroll
        for (int nt = 0; nt < 2; ++nt) {
            const int cl = wn + nt * 16 + ln;
            const float bias = bv[c0 + cl];
#pragma unroll
            for (int mt = 0; mt < 2; ++mt)
#pragma unroll
                for (int r = 0; r < 4; ++r)
                    sh.lt[cl][wm + mt * 16 + q * 4 + r] = f2bf(acc[mt][nt][r] + bias);
        }
        __syncthreads();
        const int bb = m0 >> 9, jloc = m0 & 511;
#pragma unroll
        for (int p = 0; p < 2; ++p) {
            const int idx = p * 256 + t;
            const int e_l = idx & 63, jc = (idx >> 6) * 8;
            *(uint4*)(vals_t + ((size_t)(bb * 256 + c0 + e_l)) * 512 + jloc + jc) =
                *(const uint4*)&sh.lt[e_l][jc];
        }
    }
}

// ---------------------------------------------------------------------------
// Kernel B: scores, 64i x 32j tiles (verbatim from verified baseline).
// ---------------------------------------------------------------------------
__global__ __launch_bounds__(256) void scores_k(
    const float* __restrict__ hi, const float* __restrict__ hj,
    const float* __restrict__ w2, float* __restrict__ sc)
{
    const int jt = blockIdx.x, it = blockIdx.y, bb = blockIdx.z;
    if (jt > 2 * it + 1) return;
    const int i0 = it * 64, j0 = jt * 32;
    const int t = threadIdx.x, w = t >> 6, l = t & 63;
    const int q = l >> 4, ln = l & 15;

    __shared__ __align__(16) float His[32][64];   // [h][i]
    __shared__ __align__(16) float Sst[64][36];   // output staging
    __shared__ float w2s[256];
    if (t < 64) *(float4*)&w2s[t * 4] = *(const float4*)(w2 + t * 4);

    const int si = t & 63, sh_ = (t >> 6) * 8;
    const float* hisrc = hi + (size_t)((bb << 9) + i0 + si) * 256 + sh_;
    const int jrow = w * 8 + q * 2;
    const float* hj0 = hj + (size_t)((bb << 9) + j0 + jrow) * 256;
    const float* hj1 = hj0 + 256;

    float acc00 = 0.f, acc01 = 0.f, acc10 = 0.f, acc11 = 0.f;
    float acc20 = 0.f, acc21 = 0.f, acc30 = 0.f, acc31 = 0.f;

    for (int hc = 0; hc < 256; hc += 32) {
        float4 a0 = *(const float4*)(hisrc + hc);
        float4 a1 = *(const float4*)(hisrc + hc + 4);
        float e0[32], e1[32];
#pragma unroll
        for (int c = 0; c < 8; ++c) {
            *(float4*)&e0[c * 4] = *(const float4*)(hj0 + hc + c * 4);
            *(float4*)&e1[c * 4] = *(const float4*)(hj1 + hc + c * 4);
        }
        __syncthreads();   // protect previous chunk's His reads
        His[sh_ + 0][si] = a0.x; His[sh_ + 1][si] = a0.y;
        His[sh_ + 2][si] = a0.z; His[sh_ + 3][si] = a0.w;
        His[sh_ + 4][si] = a1.x; His[sh_ + 5][si] = a1.y;
        His[sh_ + 6][si] = a1.z; His[sh_ + 7][si] = a1.w;
        __syncthreads();
#pragma unroll
        for (int h = 0; h < 32; ++h) {
            float4 a = *(const float4*)&His[h][ln * 4];
            const float wv = w2s[hc + h];
            const float f0 = e0[h], f1 = e1[h];
            acc00 += fmaxf(a.x + f0, 0.f) * wv;
            acc01 += fmaxf(a.x + f1, 0.f) * wv;
            acc10 += fmaxf(a.y + f0, 0.f) * wv;
            acc11 += fmaxf(a.y + f1, 0.f) * wv;
            acc20 += fmaxf(a.z + f0, 0.f) * wv;
            acc21 += fmaxf(a.z + f1, 0.f) * wv;
            acc30 += fmaxf(a.w + f0, 0.f) * wv;
            acc31 += fmaxf(a.w + f1, 0.f) * wv;
        }
    }

    Sst[ln * 4 + 0][jrow] = acc00;  Sst[ln * 4 + 0][jrow + 1] = acc01;
    Sst[ln * 4 + 1][jrow] = acc10;  Sst[ln * 4 + 1][jrow + 1] = acc11;
    Sst[ln * 4 + 2][jrow] = acc20;  Sst[ln * 4 + 2][jrow + 1] = acc21;
    Sst[ln * 4 + 3][jrow] = acc30;  Sst[ln * 4 + 3][jrow + 1] = acc31;
    __syncthreads();
    const int i_l = t >> 2, jc = (t & 3) * 8;
    float* dst = sc + ((size_t)bb << 18) + (size_t)(i0 + i_l) * 512 + j0 + jc;
    *(float4*)dst       = *(const float4*)&Sst[i_l][jc];
    *(float4*)(dst + 4) = *(const float4*)&Sst[i_l][jc + 4];
}

// ---------------------------------------------------------------------------
// Kernel C: fused softmax + PV + out-proj + residual + LayerNorm.
//   128 blocks; block u: b = u>>5, 16-row tile m0 = (u&31)*16.
//   softmax(sc rows) -> attnS (LDS bf16) -> PV MFMA (V streamed from L2)
//   -> msgS (LDS bf16) -> OUT MFMA -> +x +bo -> LN -> out.
// ---------------------------------------------------------------------------
__global__ __launch_bounds__(256) void smpvout_k(
    const float* __restrict__ sc, const ushort* __restrict__ vals_t,
    const ushort* __restrict__ Wot, const float* __restrict__ x,
    const float* __restrict__ bo, const float* __restrict__ gamma,
    const float* __restrict__ beta, float* __restrict__ out)
{
    const int u = blockIdx.x;
    const int b = u >> 5, m0 = (u & 31) * 16;
    const int t = threadIdx.x, w = t >> 6, l = t & 63;
    const int q = l >> 4, ln = l & 15;

    __shared__ __align__(16) ushort attnS[16][520];   // +8 pad
    __shared__ __align__(16) ushort msgS[16][264];    // +8 pad
    __shared__ float redS[16][4], redQ[16][4];

    // ---- softmax: 16 rows, 4 per wave, full-width masked read ----
    {
        const int j0 = l * 8;
#pragma unroll
        for (int rr = 0; rr < 4; ++rr) {
            const int rl = w * 4 + rr;
            const int i = m0 + rl;
            const float* srow = sc + ((size_t)b << 18) + (size_t)i * S;
            float v[8];
            *(float4*)&v[0] = *(const float4*)(srow + j0);
            *(float4*)&v[4] = *(const float4*)(srow + j0 + 4);
            float mx = -3.0e38f;
#pragma unroll
            for (int k = 0; k < 8; ++k) {
                v[k] = (j0 + k < i) ? v[k] : -3.0e38f;  // mask before ANY use
                mx = fmaxf(mx, v[k]);
            }
#pragma unroll
            for (int off = 32; off; off >>= 1) mx = fmaxf(mx, __shfl_xor(mx, off, 64));
            float e[8];
            float sum = 0.f;
#pragma unroll
            for (int k = 0; k < 8; ++k) {
                e[k] = __expf(v[k] - mx);
                sum += (j0 + k < i) ? e[k] : 0.f;
            }
#pragma unroll
            for (int off = 32; off; off >>= 1) sum += __shfl_xor(sum, off, 64);
            const float inv = (i > 0) ? (1.f / sum) : 0.f;   // row 0: all-zero
            ushort o[8];
#pragma unroll
            for (int k = 0; k < 8; ++k)
                o[k] = (j0 + k < i) ? f2bf(e[k] * inv) : (ushort)0;
            *(ushort4*)&attnS[rl][j0]     = make_ushort4(o[0], o[1], o[2], o[3]);
            *(ushort4*)&attnS[rl][j0 + 4] = make_ushort4(o[4], o[5], o[6], o[7]);
        }
    }
    __syncthreads();

    // ---- PV: msg[16][256] = attn[16][<=512] @ vals^T; wave w: cols w*64.. ----
    const ushort* V = vals_t + (size_t)b * 256 * 512;
    f32x4 acc[4] = {};
    const int kmax = (m0 + 16 + 31) & ~31;   // covers j <= m0+14
    for (int k0 = 0; k0 < kmax; k0 += 32) {
        bf16x8 a = *(const bf16x8*)&attnS[ln][k0 + q * 8];
#pragma unroll
        for (int nt = 0; nt < 4; ++nt) {
            bf16x8 bb = *(const bf16x8*)(V + (size_t)(w * 64 + nt * 16 + ln) * 512 + k0 + q * 8);
            acc[nt] = __builtin_amdgcn_mfma_f32_16x16x32_bf16(a, bb, acc[nt], 0, 0, 0);
        }
    }
#pragma unroll
    for (int nt = 0; nt < 4; ++nt)
#pragma unroll
        for (int r = 0; r < 4; ++r)
            msgS[q * 4 + r][w * 64 + nt * 16 + ln] = f2bf(acc[nt][r]);
    __syncthreads();

    // ---- OUT: out16 = msg @ Wo + bo + x, then LN ----
    f32x4 acc2[4] = {};
    for (int k0 = 0; k0 < 256; k0 += 32) {
        bf16x8 a = *(const bf16x8*)&msgS[ln][k0 + q * 8];
#pragma unroll
        for (int nt = 0; nt < 4; ++nt) {
            bf16x8 bb = *(const bf16x8*)(Wot + (size_t)(w * 64 + nt * 16 + ln) * 256 + k0 + q * 8);
            acc2[nt] = __builtin_amdgcn_mfma_f32_16x16x32_bf16(a, bb, acc2[nt], 0, 0, 0);
        }
    }

    const int r0 = (b << 9) + m0;
    float sum[4] = {}, sq[4] = {};
#pragma unroll
    for (int nt = 0; nt < 4; ++nt) {
        const int col = w * 64 + nt * 16 + ln;
        const float bov = bo[col];
#pragma unroll
        for (int r = 0; r < 4; ++r) {
            const int row = r0 + q * 4 + r;
            float v = acc2[nt][r] + x[(size_t)row * 256 + col] + bov;
            acc2[nt][r] = v;
            sum[r] += v;
            sq[r] += v * v;
        }
    }
#pragma unroll
    for (int r = 0; r < 4; ++r) {
#pragma unroll
        for (int off = 1; off < 16; off <<= 1) {
            sum[r] += __shfl_xor(sum[r], off, 64);
            sq[r]  += __shfl_xor(sq[r],  off, 64);
        }
    }
    if (ln == 0) {
#pragma unroll
        for (int r = 0; r < 4; ++r) {
            redS[q * 4 + r][w] = sum[r];
            redQ[q * 4 + r][w] = sq[r];
        }
    }
    __syncthreads();
#pragma unroll
    for (int nt = 0; nt < 4; ++nt) {
        const int col = w * 64 + nt * 16 + ln;
        const float g = gamma[col], be = beta[col];
#pragma unroll
        for (int r = 0; r < 4; ++r) {
            const int rl = q * 4 + r;
            const float ts = redS[rl][0] + redS[rl][1] + redS[rl][2] + redS[rl][3];
            const float tq = redQ[rl][0] + redQ[rl][1] + redQ[rl][2] + redQ[rl][3];
            const float mu = ts * (1.f / 256.f);
            const float var = tq * (1.f / 256.f) - mu * mu;
            out[(size_t)(r0 + rl) * 256 + col] =
                (acc2[nt][r] - mu) * rsqrtf(var + 1e-5f) * g + be;
        }
    }
}

// ---------------------------------------------------------------------------
extern "C" void kernel_launch(void* const* d_in, const int* in_sizes, int n_in,
                              void* d_out, int out_size, void* d_ws, size_t ws_size,
                              hipStream_t stream)
{
    (void)in_sizes; (void)n_in; (void)out_size; (void)ws_size;
    const float* x     = (const float*)d_in[0];
    const float* W1    = (const float*)d_in[1];
    const float* b1    = (const float*)d_in[2];
    const float* w2    = (const float*)d_in[3];
    const float* Wv    = (const float*)d_in[5];
    const float* bv    = (const float*)d_in[6];
    const float* Wo    = (const float*)d_in[7];
    const float* bo    = (const float*)d_in[8];
    const float* gamma = (const float*)d_in[9];
    const float* beta  = (const float*)d_in[10];
    float* out = (float*)d_out;

    // workspace layout in 256KB (64K-float) chunks
    float* ws = (float*)d_ws;
    float*  hi     = ws;                        // chunks 0-7   (2048*256 f32)
    float*  hj     = ws + 8 * (size_t)CH;       // chunks 8-15
    float*  sc     = ws + 16 * (size_t)CH;      // chunks 16-31 (4*512*512 f32)
    ushort* Wot    = (ushort*)(ws + 32 * (size_t)CH);  // chunk 32
    ushort* vals_t = (ushort*)(ws + 33 * (size_t)CH);  // chunks 33-36 ([b][e][j] bf16)

    qkv_pack_k<<<dim3(400),      256, 0, stream>>>(x, W1, Wv, Wo, b1, bv, hi, hj, vals_t, Wot);
    scores_k  <<<dim3(16, 8, 4), 256, 0, stream>>>(hi, hj, w2, sc);
    smpvout_k <<<dim3(128),      256, 0, stream>>>(sc, vals_t, Wot, x, bo, gamma, beta, out);
}

// Round 5
// 126.426 us; speedup vs baseline: 1.2985x; 1.0686x over previous
//
#include <hip/hip_runtime.h>
#include <math.h>

#define D 256
#define S 512
#define M 2048  // 4 * 512
#define CH (64 * 1024)  // 256KB workspace chunk in floats

typedef __attribute__((ext_vector_type(8))) short bf16x8;
typedef __attribute__((ext_vector_type(4))) float f32x4;
typedef _Float16 half2v __attribute__((ext_vector_type(2)));

__device__ inline ushort f2bf(float f) {
    union { float f; unsigned u; } v; v.f = f;
    unsigned r = v.u + 0x7FFFu + ((v.u >> 16) & 1u);   // RNE
    return (ushort)(r >> 16);
}

__device__ inline ushort f2h(float f) {
    union { _Float16 h; ushort u; } v; v.h = (_Float16)f; return v.u;
}

__device__ inline uint pack2h(float a, float b) {
    union { half2v h; uint u; } v; v.h[0] = (_Float16)a; v.h[1] = (_Float16)b;
    return v.u;
}

// relu(a + b) on packed f16 pairs (bit patterns in uint)
__device__ inline uint addrelu2(uint a, uint b) {
    union { uint u; half2v h; } x, y;
    x.u = a; y.u = b;
    half2v s = x.h + y.h;              // v_pk_add_f16
    half2v z = {};
    s = __builtin_elementwise_max(s, z);   // v_pk_max_f16
    union { half2v h; uint u; } r; r.h = s; return r.u;
}

// acc += dot2(a, b) — f32 accumulate (v_dot2_f32_f16)
__device__ inline float fdot2u(uint a, uint b, float acc) {
    union { uint u; half2v h; } x, y;
    x.u = a; y.u = b;
    return __builtin_amdgcn_fdot2(x.h, y.h, acc, false);
}

// ---------------------------------------------------------------------------
// Kernel A: fused weight-pack + QKV MFMA GEMM.
//   Blocks 0..383: gemm unit (bn = u%12 -> 64-col tile of {WA|WB|Wv}, bm = u/12
//   -> 64-row tile of x).  Packs its own B-tile (bf16 [col][k]) into LDS, runs
//   K-loop.  Outputs: hi (+b1, f16), hj (f16), vals_t (bf16 transposed).
//   Blocks 384..399: pack Wot (Wo^T bf16) for kernel C.
// ---------------------------------------------------------------------------
__global__ __launch_bounds__(256) void qkv_pack_k(
    const float* __restrict__ x, const float* __restrict__ W1,
    const float* __restrict__ Wv, const float* __restrict__ Wo,
    const float* __restrict__ b1, const float* __restrict__ bv,
    ushort* __restrict__ hi, ushort* __restrict__ hj,
    ushort* __restrict__ vals_t, ushort* __restrict__ Wot)
{
    __shared__ union {
        ushort Bs[64][264];   // packed B-tile [col_local][k], +8 pad
        ushort lt[64][72];    // transpose staging (Wot pack / vals_t store)
    } sh;

    const int u = blockIdx.x;
    const int t = threadIdx.x;

    if (u >= 384) {
        // ---- Wot pack unit (16 blocks): Wot[n][k] = bf16(Wo[k][n]) ----
        const int unit = u - 384;
        const int a0 = (unit >> 2) * 64;   // dst row block (n = src col)
        const int b0 = (unit & 3) * 64;    // dst col block (k = src row)
        const int r = t >> 4;
        const int c = (t & 15) * 4;
#pragma unroll
        for (int p = 0; p < 4; ++p) {
            const int sr = b0 + p * 16 + r;
            float4 v = *(const float4*)(Wo + (size_t)sr * 256 + a0 + c);
            sh.lt[p * 16 + r][c + 0] = f2bf(v.x);
            sh.lt[p * 16 + r][c + 1] = f2bf(v.y);
            sh.lt[p * 16 + r][c + 2] = f2bf(v.z);
            sh.lt[p * 16 + r][c + 3] = f2bf(v.w);
        }
        __syncthreads();
#pragma unroll
        for (int p = 0; p < 4; ++p) {
            const int dr = p * 16 + r;
            ushort4 o = make_ushort4(sh.lt[c + 0][dr], sh.lt[c + 1][dr],
                                     sh.lt[c + 2][dr], sh.lt[c + 3][dr]);
            *(ushort4*)(Wot + (size_t)(a0 + dr) * 256 + b0 + c) = o;
        }
        return;
    }

    // ---- QKV gemm unit ----
    const int bn = u % 12, bm = u / 12;
    const int n0 = bn * 64, m0 = bm * 64;
    const int region = n0 >> 8, c0 = n0 & 255;

    // pack B-tile into LDS: Bs[cl][k] = bf16(Wsrc[k][c0+cl])
    {
        const int cl4 = (t & 15) * 4;
        const int kb = (t >> 4) * 16;
#pragma unroll
        for (int kk = 0; kk < 16; ++kk) {
            const int k = kb + kk;
            float4 v;
            if (region == 0) {
                float4 wa = *(const float4*)(W1 + (size_t)k * 256 + c0 + cl4);
                float4 wc = *(const float4*)(W1 + (size_t)(512 + k) * 256 + c0 + cl4);
                v = make_float4(wa.x + wc.x, wa.y + wc.y, wa.z + wc.z, wa.w + wc.w);
            } else if (region == 1) {
                float4 wb = *(const float4*)(W1 + (size_t)(256 + k) * 256 + c0 + cl4);
                float4 wc = *(const float4*)(W1 + (size_t)(512 + k) * 256 + c0 + cl4);
                v = make_float4(wb.x - wc.x, wb.y - wc.y, wb.z - wc.z, wb.w - wc.w);
            } else {
                v = *(const float4*)(Wv + (size_t)k * 256 + c0 + cl4);
            }
            sh.Bs[cl4 + 0][k] = f2bf(v.x);
            sh.Bs[cl4 + 1][k] = f2bf(v.y);
            sh.Bs[cl4 + 2][k] = f2bf(v.z);
            sh.Bs[cl4 + 3][k] = f2bf(v.w);
        }
    }
    __syncthreads();

    const int w = t >> 6, l = t & 63;
    const int q = l >> 4, ln = l & 15;
    const int wm = (w >> 1) * 32, wn = (w & 1) * 32;

    f32x4 acc[2][2] = {};
    for (int k0 = 0; k0 < 256; k0 += 32) {
        union { bf16x8 v; ushort s[8]; } a[2];
        bf16x8 b[2];
#pragma unroll
        for (int mt = 0; mt < 2; ++mt) {
            const float* xr = x + (size_t)(m0 + wm + mt * 16 + ln) * 256 + k0 + q * 8;
            float4 u0 = *(const float4*)xr;
            float4 u1 = *(const float4*)(xr + 4);
            a[mt].s[0] = f2bf(u0.x); a[mt].s[1] = f2bf(u0.y);
            a[mt].s[2] = f2bf(u0.z); a[mt].s[3] = f2bf(u0.w);
            a[mt].s[4] = f2bf(u1.x); a[mt].s[5] = f2bf(u1.y);
            a[mt].s[6] = f2bf(u1.z); a[mt].s[7] = f2bf(u1.w);
        }
#pragma unroll
        for (int nt = 0; nt < 2; ++nt)
            b[nt] = *(const bf16x8*)&sh.Bs[wn + nt * 16 + ln][k0 + q * 8];
#pragma unroll
        for (int mt = 0; mt < 2; ++mt)
#pragma unroll
            for (int nt = 0; nt < 2; ++nt)
                acc[mt][nt] = __builtin_amdgcn_mfma_f32_16x16x32_bf16(a[mt].v, b[nt], acc[mt][nt], 0, 0, 0);
    }

    if (region < 2) {
        ushort* dst = (region == 0) ? hi : hj;
#pragma unroll
        for (int nt = 0; nt < 2; ++nt) {
            const int col = c0 + wn + nt * 16 + ln;
            const float bias = (region == 0) ? b1[col] : 0.f;
#pragma unroll
            for (int mt = 0; mt < 2; ++mt)
#pragma unroll
                for (int r = 0; r < 4; ++r) {
                    const int row = m0 + wm + mt * 16 + q * 4 + r;
                    dst[(size_t)row * 256 + col] = f2h(acc[mt][nt][r] + bias);
                }
        }
    } else {
        // stage bias-added bf16 into lt[col_local][row_local], store transposed
        __syncthreads();   // all Bs reads done before aliasing as lt
#pragma unroll
        for (int nt = 0; nt < 2; ++nt) {
            const int cl = wn + nt * 16 + ln;
            const float bias = bv[c0 + cl];
#pragma unroll
            for (int mt = 0; mt < 2; ++mt)
#pragma unroll
                for (int r = 0; r < 4; ++r)
                    sh.lt[cl][wm + mt * 16 + q * 4 + r] = f2bf(acc[mt][nt][r] + bias);
        }
        __syncthreads();
        const int bb = m0 >> 9, jloc = m0 & 511;
#pragma unroll
        for (int p = 0; p < 2; ++p) {
            const int idx = p * 256 + t;
            const int e_l = idx & 63, jc = (idx >> 6) * 8;
            *(uint4*)(vals_t + ((size_t)(bb * 256 + c0 + e_l)) * 512 + jloc + jc) =
                *(const uint4*)&sh.lt[e_l][jc];
        }
    }
}

// ---------------------------------------------------------------------------
// Kernel B: scores, 64i x 32j tiles, packed-f16 inner loop (v_dot2_f32_f16).
//   hi/hj are f16.  His2u: LDS [h_pair][i] as packed half2.  Per h-pair per
//   thread: 8 pk_add + 8 pk_max + 8 dot2 = 24 instrs for 2 h (2x f32 version).
// ---------------------------------------------------------------------------
__global__ __launch_bounds__(256) void scores_k(
    const ushort* __restrict__ hi, const ushort* __restrict__ hj,
    const float* __restrict__ w2, float* __restrict__ sc)
{
    const int jt = blockIdx.x, it = blockIdx.y, bb = blockIdx.z;
    if (jt > 2 * it + 1) return;
    const int i0 = it * 64, j0 = jt * 32;
    const int t = threadIdx.x, w = t >> 6, l = t & 63;
    const int q = l >> 4, ln = l & 15;

    __shared__ __align__(16) uint His2u[16][64];   // [h_pair][i], packed half2
    __shared__ __align__(16) float Sst[64][36];    // output staging
    __shared__ uint w2u[128];                      // w2 packed half2
    if (t < 64) {
        float4 wv = *(const float4*)(w2 + t * 4);
        w2u[t * 2 + 0] = pack2h(wv.x, wv.y);
        w2u[t * 2 + 1] = pack2h(wv.z, wv.w);
    }

    const int si = t & 63, sh_ = (t >> 6) * 8;
    const ushort* hisrc = hi + (size_t)((bb << 9) + i0 + si) * 256 + sh_;
    const int jrow = w * 8 + q * 2;
    const ushort* hj0 = hj + (size_t)((bb << 9) + j0 + jrow) * 256;
    const ushort* hj1 = hj0 + 256;

    float acc00 = 0.f, acc01 = 0.f, acc10 = 0.f, acc11 = 0.f;
    float acc20 = 0.f, acc21 = 0.f, acc30 = 0.f, acc31 = 0.f;

    for (int hc = 0; hc < 256; hc += 32) {
        uint4 a = *(const uint4*)(hisrc + hc);    // 8 halves = 4 half2 pairs
        uint e0u[16], e1u[16];
#pragma unroll
        for (int c = 0; c < 4; ++c) {
            *(uint4*)&e0u[c * 4] = *(const uint4*)(hj0 + hc + c * 8);
            *(uint4*)&e1u[c * 4] = *(const uint4*)(hj1 + hc + c * 8);
        }
        __syncthreads();   // protect previous chunk's His2u reads
        const int hp0 = sh_ >> 1;
        His2u[hp0 + 0][si] = a.x;
        His2u[hp0 + 1][si] = a.y;
        His2u[hp0 + 2][si] = a.z;
        His2u[hp0 + 3][si] = a.w;
        __syncthreads();
#pragma unroll
        for (int hp = 0; hp < 16; ++hp) {
            uint4 av = *(const uint4*)&His2u[hp][ln * 4];
            const uint wv = w2u[(hc >> 1) + hp];
            const uint f0 = e0u[hp], f1 = e1u[hp];
            acc00 = fdot2u(addrelu2(av.x, f0), wv, acc00);
            acc01 = fdot2u(addrelu2(av.x, f1), wv, acc01);
            acc10 = fdot2u(addrelu2(av.y, f0), wv, acc10);
            acc11 = fdot2u(addrelu2(av.y, f1), wv, acc11);
            acc20 = fdot2u(addrelu2(av.z, f0), wv, acc20);
            acc21 = fdot2u(addrelu2(av.z, f1), wv, acc21);
            acc30 = fdot2u(addrelu2(av.w, f0), wv, acc30);
            acc31 = fdot2u(addrelu2(av.w, f1), wv, acc31);
        }
    }

    Sst[ln * 4 + 0][jrow] = acc00;  Sst[ln * 4 + 0][jrow + 1] = acc01;
    Sst[ln * 4 + 1][jrow] = acc10;  Sst[ln * 4 + 1][jrow + 1] = acc11;
    Sst[ln * 4 + 2][jrow] = acc20;  Sst[ln * 4 + 2][jrow + 1] = acc21;
    Sst[ln * 4 + 3][jrow] = acc30;  Sst[ln * 4 + 3][jrow + 1] = acc31;
    __syncthreads();
    const int i_l = t >> 2, jc = (t & 3) * 8;
    float* dst = sc + ((size_t)bb << 18) + (size_t)(i0 + i_l) * 512 + j0 + jc;
    *(float4*)dst       = *(const float4*)&Sst[i_l][jc];
    *(float4*)(dst + 4) = *(const float4*)&Sst[i_l][jc + 4];
}

// ---------------------------------------------------------------------------
// Kernel C: fused softmax + PV + out-proj + residual + LayerNorm.
//   256 blocks x 512 threads; block u: b = u>>6, 8-row tile m0 = (u&63)*8.
//   All CUs active, 2 waves/SIMD (was 128 blocks, half the CUs at 1 wave/SIMD).
//   MFMA M=16 runs with rows 8..15 zeroed (waste is ~free; MFMA total <1us).
// ---------------------------------------------------------------------------
__global__ __launch_bounds__(512) void smpvout_k(
    const float* __restrict__ sc, const ushort* __restrict__ vals_t,
    const ushort* __restrict__ Wot, const float* __restrict__ x,
    const float* __restrict__ bo, const float* __restrict__ gamma,
    const float* __restrict__ beta, float* __restrict__ out)
{
    const int u = blockIdx.x;
    const int b = u >> 6, m0 = (u & 63) * 8;
    const int t = threadIdx.x, w = t >> 6, l = t & 63;
    const int q = l >> 4, ln = l & 15;

    __shared__ __align__(16) ushort attnS[16][520];   // +8 pad
    __shared__ __align__(16) ushort msgS[16][264];    // +8 pad
    __shared__ float redS[8][8], redQ[8][8];

    // zero attnS rows 8..15 (512 threads x 8 ushorts)
    *(uint4*)&attnS[8 + (t >> 6)][(t & 63) * 8] = make_uint4(0, 0, 0, 0);

    // ---- softmax: 8 rows, one per wave ----
    {
        const int i = m0 + w;
        const float* srow = sc + ((size_t)b << 18) + (size_t)i * S;
        const int j0 = l * 8;
        float v[8];
        *(float4*)&v[0] = *(const float4*)(srow + j0);
        *(float4*)&v[4] = *(const float4*)(srow + j0 + 4);
        float mx = -3.0e38f;
#pragma unroll
        for (int k = 0; k < 8; ++k) {
            v[k] = (j0 + k < i) ? v[k] : -3.0e38f;  // mask before ANY use
            mx = fmaxf(mx, v[k]);
        }
#pragma unroll
        for (int off = 32; off; off >>= 1) mx = fmaxf(mx, __shfl_xor(mx, off, 64));
        float e[8];
        float sum = 0.f;
#pragma unroll
        for (int k = 0; k < 8; ++k) {
            e[k] = __expf(v[k] - mx);
            sum += (j0 + k < i) ? e[k] : 0.f;
        }
#pragma unroll
        for (int off = 32; off; off >>= 1) sum += __shfl_xor(sum, off, 64);
        const float inv = (i > 0) ? (1.f / sum) : 0.f;   // row 0: all-zero
        ushort o[8];
#pragma unroll
        for (int k = 0; k < 8; ++k)
            o[k] = (j0 + k < i) ? f2bf(e[k] * inv) : (ushort)0;
        *(ushort4*)&attnS[w][j0]     = make_ushort4(o[0], o[1], o[2], o[3]);
        *(ushort4*)&attnS[w][j0 + 4] = make_ushort4(o[4], o[5], o[6], o[7]);
    }
    __syncthreads();

    // ---- PV: wave w -> cols w*32..w*32+31 (nt 0..1) ----
    const ushort* V = vals_t + (size_t)b * 256 * 512;
    f32x4 acc[2] = {};
    const int kmax = (m0 + 8 + 31) & ~31;   // covers j <= m0+6
    for (int k0 = 0; k0 < kmax; k0 += 32) {
        bf16x8 a = *(const bf16x8*)&attnS[ln][k0 + q * 8];
#pragma unroll
        for (int nt = 0; nt < 2; ++nt) {
            bf16x8 bb = *(const bf16x8*)(V + (size_t)(w * 32 + nt * 16 + ln) * 512 + k0 + q * 8);
            acc[nt] = __builtin_amdgcn_mfma_f32_16x16x32_bf16(a, bb, acc[nt], 0, 0, 0);
        }
    }
#pragma unroll
    for (int nt = 0; nt < 2; ++nt)
#pragma unroll
        for (int r = 0; r < 4; ++r)
            msgS[q * 4 + r][w * 32 + nt * 16 + ln] = f2bf(acc[nt][r]);
    __syncthreads();

    // ---- OUT: wave w -> cols w*32..w*32+31; rows 0..7 valid ----
    f32x4 acc2[2] = {};
    for (int k0 = 0; k0 < 256; k0 += 32) {
        bf16x8 a = *(const bf16x8*)&msgS[ln][k0 + q * 8];
#pragma unroll
        for (int nt = 0; nt < 2; ++nt) {
            bf16x8 bb = *(const bf16x8*)(Wot + (size_t)(w * 32 + nt * 16 + ln) * 256 + k0 + q * 8);
            acc2[nt] = __builtin_amdgcn_mfma_f32_16x16x32_bf16(a, bb, acc2[nt], 0, 0, 0);
        }
    }

    const int r0 = (b << 9) + m0;
    float sum[4] = {}, sq[4] = {};
    if (q < 2) {
#pragma unroll
        for (int nt = 0; nt < 2; ++nt) {
            const int col = w * 32 + nt * 16 + ln;
            const float bov = bo[col];
#pragma unroll
            for (int r = 0; r < 4; ++r) {
                const int row = r0 + q * 4 + r;
                float v = acc2[nt][r] + x[(size_t)row * 256 + col] + bov;
                acc2[nt][r] = v;
                sum[r] += v;
                sq[r] += v * v;
            }
        }
    }
#pragma unroll
    for (int r = 0; r < 4; ++r) {
#pragma unroll
        for (int off = 1; off < 16; off <<= 1) {
            sum[r] += __shfl_xor(sum[r], off, 64);
            sq[r]  += __shfl_xor(sq[r],  off, 64);
        }
    }
    if (ln == 0 && q < 2) {
#pragma unroll
        for (int r = 0; r < 4; ++r) {
            redS[q * 4 + r][w] = sum[r];
            redQ[q * 4 + r][w] = sq[r];
        }
    }
    __syncthreads();
    if (q < 2) {
#pragma unroll
        for (int nt = 0; nt < 2; ++nt) {
            const int col = w * 32 + nt * 16 + ln;
            const float g = gamma[col], be = beta[col];
#pragma unroll
            for (int r = 0; r < 4; ++r) {
                const int rl = q * 4 + r;
                float ts = 0.f, tq = 0.f;
#pragma unroll
                for (int k = 0; k < 8; ++k) { ts += redS[rl][k]; tq += redQ[rl][k]; }
                const float mu = ts * (1.f / 256.f);
                const float var = tq * (1.f / 256.f) - mu * mu;
                out[(size_t)(r0 + rl) * 256 + col] =
                    (acc2[nt][r] - mu) * rsqrtf(var + 1e-5f) * g + be;
            }
        }
    }
}

// ---------------------------------------------------------------------------
extern "C" void kernel_launch(void* const* d_in, const int* in_sizes, int n_in,
                              void* d_out, int out_size, void* d_ws, size_t ws_size,
                              hipStream_t stream)
{
    (void)in_sizes; (void)n_in; (void)out_size; (void)ws_size;
    const float* x     = (const float*)d_in[0];
    const float* W1    = (const float*)d_in[1];
    const float* b1    = (const float*)d_in[2];
    const float* w2    = (const float*)d_in[3];
    const float* Wv    = (const float*)d_in[5];
    const float* bv    = (const float*)d_in[6];
    const float* Wo    = (const float*)d_in[7];
    const float* bo    = (const float*)d_in[8];
    const float* gamma = (const float*)d_in[9];
    const float* beta  = (const float*)d_in[10];
    float* out = (float*)d_out;

    // workspace layout in 256KB (64K-float) chunks
    float* ws = (float*)d_ws;
    ushort* hi     = (ushort*)ws;                      // chunks 0-7 (f16 now)
    ushort* hj     = (ushort*)(ws + 8 * (size_t)CH);   // chunks 8-15
    float*  sc     = ws + 16 * (size_t)CH;             // chunks 16-31 (4*512*512 f32)
    ushort* Wot    = (ushort*)(ws + 32 * (size_t)CH);  // chunk 32
    ushort* vals_t = (ushort*)(ws + 33 * (size_t)CH);  // chunks 33-36 ([b][e][j] bf16)

    qkv_pack_k<<<dim3(400),      256, 0, stream>>>(x, W1, Wv, Wo, b1, bv, hi, hj, vals_t, Wot);
    scores_k  <<<dim3(16, 8, 4), 256, 0, stream>>>(hi, hj, w2, sc);
    smpvout_k <<<dim3(256),      512, 0, stream>>>(sc, vals_t, Wot, x, bo, gamma, beta, out);
}